// Round 1
// baseline (1994.916 us; speedup 1.0000x reference)
//
#include <hip/hip_runtime.h>
#include <hip/hip_bf16.h>

#define B_ 4
#define N_ 16384
#define HID_ 512
#define H_ 8
#define M_ 32
#define D_ 64
#define HM_ 256

typedef __hip_bfloat16 bf16;

// ---------------- K_wfused: Wfused^T[k][o] = sum_m mix1_w[o, h*32+m] * wtq[h,m,d], k=h*64+d
__global__ __launch_bounds__(256) void k_wfused(const float* __restrict__ mix1,
        const float* __restrict__ wtq, float* __restrict__ wfT) {
    const int idx = blockIdx.x * 256 + threadIdx.x;   // < 131072
    const int k = idx >> 8, o = idx & 255;
    const int h = k >> 6, dd = k & 63;
    float s = 0.f;
#pragma unroll
    for (int m = 0; m < 32; ++m)
        s += mix1[(long long)o * 256 + h * 32 + m] * wtq[((long long)h * 32 + m) * 64 + dd];
    wfT[(long long)k * 256 + o] = s;
}

// ---------------- K1: kv = x @ wkv^T + bkv -> xk,xv bf16, layout [b*N+n][512]
__global__ __launch_bounds__(256) void k1_kv(const float* __restrict__ x,
        const float* __restrict__ wkv, const float* __restrict__ bkv,
        bf16* __restrict__ xk, bf16* __restrict__ xv) {
    __shared__ __align__(16) float As[16][68];
    __shared__ __align__(16) float Bs[16][68];
    const int t = threadIdx.x;
    const int tx = t & 15, ty = t >> 4;
    const int col0 = blockIdx.x * 64;
    const long long row0 = (long long)blockIdx.y * 64;
    float acc[4][4] = {};
    for (int k0 = 0; k0 < 512; k0 += 16) {
#pragma unroll
        for (int i = 0; i < 4; ++i) {
            int flat = i * 256 + t;
            int rl = flat >> 4, k = flat & 15;
            As[k][rl] = x[(row0 + rl) * 512 + k0 + k];
        }
#pragma unroll
        for (int i = 0; i < 4; ++i) {
            int flat = i * 256 + t;
            int ol = flat >> 4, k = flat & 15;
            Bs[k][ol] = wkv[(long long)(col0 + ol) * 512 + k0 + k];
        }
        __syncthreads();
#pragma unroll
        for (int k = 0; k < 16; ++k) {
            float4 av = *reinterpret_cast<const float4*>(&As[k][ty * 4]);
            float4 bv = *reinterpret_cast<const float4*>(&Bs[k][tx * 4]);
            float ar[4] = {av.x, av.y, av.z, av.w};
            float br[4] = {bv.x, bv.y, bv.z, bv.w};
#pragma unroll
            for (int i = 0; i < 4; ++i)
#pragma unroll
                for (int j = 0; j < 4; ++j)
                    acc[i][j] += ar[i] * br[j];
        }
        __syncthreads();
    }
#pragma unroll
    for (int i = 0; i < 4; ++i) {
        long long row = row0 + ty * 4 + i;
#pragma unroll
        for (int j = 0; j < 4; ++j) {
            int col = col0 + tx * 4 + j;
            float v = acc[i][j] + bkv[col];
            bf16 hv = __float2bfloat16(v);
            if (col < 512) xk[row * 512 + col] = hv;
            else           xv[row * 512 + (col - 512)] = hv;
        }
    }
}

// ---------------- K2: mixed scores GEMM (xk @ Wfused^T) + group softmax -> sw (B,H,M,N) in d_out
__global__ __launch_bounds__(256) void k2_sw(const bf16* __restrict__ xk,
        const float* __restrict__ wfT, const float* __restrict__ alpha1,
        float* __restrict__ swout) {
    __shared__ float Ws[16][256];
    __shared__ __align__(16) float As[16][20];
    __shared__ float sws[256][17];
    const int t = threadIdx.x;
    const int n0 = blockIdx.x * 16;
    const int b = blockIdx.y;
    const long long rowbase = (long long)b * N_ + n0;
    float acc[16] = {};
    for (int k0 = 0; k0 < 512; k0 += 16) {
        {   int r = t >> 4, k = t & 15;
            As[r][k] = __bfloat162float(xk[(rowbase + r) * 512 + k0 + k]); }
#pragma unroll
        for (int i = 0; i < 16; ++i)
            Ws[i][t] = wfT[(long long)(k0 + i) * 256 + t];
        __syncthreads();
        float wreg[16];
#pragma unroll
        for (int k = 0; k < 16; ++k) wreg[k] = Ws[k][t];
#pragma unroll
        for (int r = 0; r < 16; ++r) {
#pragma unroll
            for (int k4 = 0; k4 < 4; ++k4) {
                float4 a = *reinterpret_cast<const float4*>(&As[r][k4 * 4]);
                acc[r] += a.x * wreg[k4 * 4] + a.y * wreg[k4 * 4 + 1]
                        + a.z * wreg[k4 * 4 + 2] + a.w * wreg[k4 * 4 + 3];
            }
        }
        __syncthreads();
    }
    const float al = alpha1[t >> 5];
#pragma unroll
    for (int r = 0; r < 16; ++r) {
        float v = acc[r] * al;
        float mx = v;
#pragma unroll
        for (int mk = 16; mk >= 1; mk >>= 1) mx = fmaxf(mx, __shfl_xor(mx, mk, 32));
        float e = __expf(v - mx);
        float s = e;
#pragma unroll
        for (int mk = 16; mk >= 1; mk >>= 1) s += __shfl_xor(s, mk, 32);
        sws[t][r] = e / s;
    }
    __syncthreads();
#pragma unroll
    for (int j = 0; j < 16; ++j) {
        int o = j * 16 + (t >> 4);
        int nl = t & 15;
        swout[((long long)b * HM_ + o) * N_ + n0 + nl] = sws[o][nl];
    }
}

// ---------------- swsum[b,h,m] = sum_n sw
__global__ __launch_bounds__(256) void k_swsum(const float* __restrict__ sw,
        float* __restrict__ swsum) {
    __shared__ float red[256];
    const int t = threadIdx.x;
    const long long base = (long long)blockIdx.x * N_;
    float s = 0.f;
    for (int i = 0; i < N_ / 256; ++i) s += sw[base + i * 256 + t];
    red[t] = s; __syncthreads();
    for (int w = 128; w >= 1; w >>= 1) {
        if (t < w) red[t] += red[t + w];
        __syncthreads();
    }
    if (t == 0) swsum[blockIdx.x] = red[0];
}

// ---------------- K3: tok partials over n-chunks: tok_part[bh][chunk][m][d]
__global__ __launch_bounds__(256) void k3_tok(const float* __restrict__ sw,
        const bf16* __restrict__ xv, float* __restrict__ tok_part) {
    __shared__ __align__(16) float swsT[256][36];   // [nl][m], padded; also reused as reduce buf
    const int t = threadIdx.x;
    const int d = t & 63, g = t >> 6;
    const int chunk = blockIdx.x;   // 64 chunks of 256 n
    const int bh = blockIdx.y;      // 32
    const int n0 = chunk * 256;
    const int b = bh >> 3, h = bh & 7;
#pragma unroll
    for (int i = 0; i < 32; ++i)
        swsT[t][i] = sw[((long long)bh * 32 + i) * N_ + n0 + t];
    __syncthreads();
    float acc[32] = {};
    const long long xvbase = ((long long)b * N_ + n0 + g * 64) * 512 + h * 64 + d;
    for (int ni = 0; ni < 64; ++ni) {
        int nl = g * 64 + ni;
        float xvv = __bfloat162float(xv[xvbase + (long long)ni * 512]);
#pragma unroll
        for (int m4 = 0; m4 < 8; ++m4) {
            float4 s4 = *reinterpret_cast<const float4*>(&swsT[nl][m4 * 4]);
            acc[m4 * 4 + 0] += s4.x * xvv;
            acc[m4 * 4 + 1] += s4.y * xvv;
            acc[m4 * 4 + 2] += s4.z * xvv;
            acc[m4 * 4 + 3] += s4.w * xvv;
        }
    }
    __syncthreads();
    float* red = &swsT[0][0];       // need 8192 floats <= 9216 available
#pragma unroll
    for (int m = 0; m < 32; ++m) red[(g * 32 + m) * 64 + d] = acc[m];
    __syncthreads();
#pragma unroll
    for (int i = 0; i < 8; ++i) {
        int idx = i * 256 + t;
        int m = idx >> 6, dd = idx & 63;
        float s = red[m * 64 + dd] + red[(32 + m) * 64 + dd]
                + red[(64 + m) * 64 + dd] + red[(96 + m) * 64 + dd];
        tok_part[(((long long)bh * 64 + chunk) * 32 + m) * 64 + dd] = s;
    }
}

// ---------------- K4a: sum chunks, normalize by swsum, LayerNorm(D=64) -> tok_ln (B,M,HID)
__global__ __launch_bounds__(64) void k4a_ln(const float* __restrict__ tok_part,
        const float* __restrict__ swsum, const float* __restrict__ ln_w,
        const float* __restrict__ ln_b, float* __restrict__ tok_ln) {
    const int bid = blockIdx.x;           // bh*32 + m
    const int bh = bid >> 5, m = bid & 31;
    const int d = threadIdx.x;
    float s = 0.f;
    for (int ch = 0; ch < 64; ++ch)
        s += tok_part[(((long long)bh * 64 + ch) * 32 + m) * 64 + d];
    float tokv = s / (swsum[bid] + 1e-5f);
    float mu = tokv;
#pragma unroll
    for (int mk = 32; mk >= 1; mk >>= 1) mu += __shfl_xor(mu, mk, 64);
    mu *= (1.f / 64.f);
    float df = tokv - mu;
    float var = df * df;
#pragma unroll
    for (int mk = 32; mk >= 1; mk >>= 1) var += __shfl_xor(var, mk, 64);
    var *= (1.f / 64.f);
    float y = df * rsqrtf(var + 1e-5f) * ln_w[d] + ln_b[d];
    const int b = bh >> 3, h = bh & 7;
    tok_ln[((long long)b * 32 + m) * 512 + h * 64 + d] = y;
}

// ---------------- K4b: qkv = tok_ln @ wqkv^T  (tiny: 128 x 1536 x 512)
__global__ __launch_bounds__(256) void k4b_qkv(const float* __restrict__ tok_ln,
        const float* __restrict__ wqkv, float* __restrict__ qkv) {
    const int idx = blockIdx.x * 256 + threadIdx.x;  // < 196608
    const int row = idx / 1536, j = idx % 1536;
    float s = 0.f;
    for (int k = 0; k < 512; ++k)
        s += tok_ln[(long long)row * 512 + k] * wqkv[(long long)j * 512 + k];
    qkv[idx] = s;
}

// ---------------- K4c: inner MHA over M=32 tokens per (b,h); writes attn to d_out
__global__ __launch_bounds__(256) void k4c_attn(const float* __restrict__ qkv,
        float* __restrict__ out_tok, float* __restrict__ attn_out) {
    __shared__ float qsT[64][33], ksT[64][33], vsT[64][33];
    __shared__ float att[32][33];
    __shared__ float rinv[32];
    const int t = threadIdx.x;
    const int bid = blockIdx.x;     // b*8+h
    const int b = bid >> 3, h = bid & 7;
#pragma unroll
    for (int i = 0; i < 8; ++i) {
        int idx = i * 256 + t;
        int mi = idx >> 6, dd = idx & 63;
        long long base = ((long long)b * 32 + mi) * 1536 + h * 64 + dd;
        qsT[dd][mi] = qkv[base];
        ksT[dd][mi] = qkv[base + 512];
        vsT[dd][mi] = qkv[base + 1024];
    }
    __syncthreads();
#pragma unroll
    for (int i = 0; i < 4; ++i) {
        int idx = i * 256 + t;
        int qi = idx >> 5, ki = idx & 31;
        float s = 0.f;
#pragma unroll
        for (int dd = 0; dd < 64; ++dd) s += qsT[dd][qi] * ksT[dd][ki];
        att[qi][ki] = s * 0.125f;
    }
    __syncthreads();
    if (t < 32) {
        float mx = -1e30f;
        for (int k = 0; k < 32; ++k) mx = fmaxf(mx, att[t][k]);
        float sum = 0.f;
        for (int k = 0; k < 32; ++k) { float e = __expf(att[t][k] - mx); att[t][k] = e; sum += e; }
        rinv[t] = 1.f / sum;
    }
    __syncthreads();
#pragma unroll
    for (int i = 0; i < 4; ++i) {
        int idx = i * 256 + t;
        int qi = idx >> 5, ki = idx & 31;
        float a = att[qi][ki] * rinv[qi];
        att[qi][ki] = a;
        attn_out[(long long)bid * 1024 + qi * 32 + ki] = a;
    }
    __syncthreads();
#pragma unroll
    for (int i = 0; i < 8; ++i) {
        int idx = i * 256 + t;
        int qi = idx >> 6, dd = idx & 63;
        float s = 0.f;
#pragma unroll
        for (int ki = 0; ki < 32; ++ki) s += att[qi][ki] * vsT[dd][ki];
        out_tok[((long long)bid * 32 + qi) * 64 + dd] = s;
    }
}

// ---------------- K5: W2[b,o,c] = sum_d wout[o, h*64+d] * out_tok[b,h,m,d], c=h*32+m
__global__ __launch_bounds__(256) void k5_w2(const float* __restrict__ wout,
        const float* __restrict__ out_tok, float* __restrict__ W2) {
    const int bid = blockIdx.x;          // b*512 + o
    const int b = bid >> 9, o = bid & 511;
    const int t = threadIdx.x;           // c
    const int h = t >> 5, m = t & 31;
    float s = 0.f;
#pragma unroll
    for (int dd = 0; dd < 64; ++dd)
        s += wout[(long long)o * 512 + h * 64 + dd]
           * out_tok[(((long long)b * 8 + h) * 32 + m) * 64 + dd];
    W2[(long long)bid * 256 + t] = s;
}

// ---------------- K6: out[b,n,o] = sum_c W2[b,o,c]*sw[b,c,n] + bout[o]
__global__ __launch_bounds__(256) void k6_out(const float* __restrict__ sw,
        const float* __restrict__ W2, const float* __restrict__ bout,
        float* __restrict__ out) {
    __shared__ __align__(16) float As[16][68];
    __shared__ __align__(16) float Bs[16][68];
    const int t = threadIdx.x;
    const int tx = t & 15, ty = t >> 4;
    const int o0 = blockIdx.x * 64;
    const int n0 = blockIdx.y * 64;
    const int b = blockIdx.z;
    float acc[4][4] = {};
    for (int c0 = 0; c0 < 256; c0 += 16) {
#pragma unroll
        for (int i = 0; i < 4; ++i) {
            int flat = i * 256 + t;
            int k = flat >> 6, nl = flat & 63;
            As[k][nl] = sw[((long long)b * HM_ + c0 + k) * N_ + n0 + nl];
        }
#pragma unroll
        for (int i = 0; i < 4; ++i) {
            int flat = i * 256 + t;
            int ol = flat >> 4, k = flat & 15;
            Bs[k][ol] = W2[((long long)b * 512 + o0 + ol) * 256 + c0 + k];
        }
        __syncthreads();
#pragma unroll
        for (int k = 0; k < 16; ++k) {
            float4 av = *reinterpret_cast<const float4*>(&As[k][ty * 4]);
            float4 bv = *reinterpret_cast<const float4*>(&Bs[k][tx * 4]);
            float ar[4] = {av.x, av.y, av.z, av.w};
            float br[4] = {bv.x, bv.y, bv.z, bv.w};
#pragma unroll
            for (int i = 0; i < 4; ++i)
#pragma unroll
                for (int j = 0; j < 4; ++j)
                    acc[i][j] += ar[i] * br[j];
        }
        __syncthreads();
    }
#pragma unroll
    for (int i = 0; i < 4; ++i) {
        long long n = n0 + ty * 4 + i;
        float4 o4;
        o4.x = acc[i][0] + bout[o0 + tx * 4 + 0];
        o4.y = acc[i][1] + bout[o0 + tx * 4 + 1];
        o4.z = acc[i][2] + bout[o0 + tx * 4 + 2];
        o4.w = acc[i][3] + bout[o0 + tx * 4 + 3];
        *reinterpret_cast<float4*>(&out[((long long)b * N_ + n) * 512 + o0 + tx * 4]) = o4;
    }
}

// ---------------- misc outputs: alpha1 copy + zeros
__global__ void k_misc(const float* __restrict__ alpha1,
        float* __restrict__ outA, float* __restrict__ outZ) {
    int t = threadIdx.x;
    if (t < 8) outA[t] = alpha1[t];
    outZ[t] = 0.f;
}

extern "C" void kernel_launch(void* const* d_in, const int* in_sizes, int n_in,
                              void* d_out, int out_size, void* d_ws, size_t ws_size,
                              hipStream_t stream) {
    const float* x      = (const float*)d_in[0];
    const float* wkv    = (const float*)d_in[1];
    const float* bkv    = (const float*)d_in[2];
    const float* wtq    = (const float*)d_in[3];
    const float* alpha1 = (const float*)d_in[4];
    const float* mix1_w = (const float*)d_in[5];
    const float* ln1_w  = (const float*)d_in[6];
    const float* ln1_b  = (const float*)d_in[7];
    const float* wqkv   = (const float*)d_in[8];
    const float* wout   = (const float*)d_in[9];
    const float* bout   = (const float*)d_in[10];

    float* out   = (float*)d_out;
    float* swout = out + 33554432LL;     // (B,H,M,N)
    float* alphaO = out + 50331648LL;    // 8
    float* zerosO = out + 50331656LL;    // 256
    float* attnO  = out + 50331912LL;    // (B,H,M,M)

    char* ws = (char*)d_ws;
    bf16*  xk       = (bf16*)(ws);                       //  64 MiB
    bf16*  xv       = (bf16*)(ws + 67108864LL);          //  64 MiB
    float* tok_part = (float*)(ws + 134217728LL);        //  16 MiB
    float* swsum    = (float*)(ws + 150994944LL);        //   4 KiB
    float* tok_ln   = (float*)(ws + 150999040LL);        // 256 KiB
    float* qkv      = (float*)(ws + 151261184LL);        // 768 KiB
    float* out_tok  = (float*)(ws + 152047616LL);        // 256 KiB
    float* W2       = (float*)(ws + 152309760LL);        //   2 MiB
    float* wfT      = (float*)(ws + 154406912LL);        // 512 KiB

    k_wfused<<<512, 256, 0, stream>>>(mix1_w, wtq, wfT);
    k1_kv<<<dim3(16, 1024), 256, 0, stream>>>(x, wkv, bkv, xk, xv);
    k2_sw<<<dim3(1024, 4), 256, 0, stream>>>(xk, wfT, alpha1, swout);
    k_swsum<<<1024, 256, 0, stream>>>(swout, swsum);
    k3_tok<<<dim3(64, 32), 256, 0, stream>>>(swout, xv, tok_part);
    k4a_ln<<<1024, 64, 0, stream>>>(tok_part, swsum, ln1_w, ln1_b, tok_ln);
    k4b_qkv<<<768, 256, 0, stream>>>(tok_ln, wqkv, qkv);
    k4c_attn<<<32, 256, 0, stream>>>(qkv, out_tok, attnO);
    k5_w2<<<2048, 256, 0, stream>>>(wout, out_tok, W2);
    k6_out<<<dim3(8, 256, 4), 256, 0, stream>>>(swout, W2, bout, out);
    k_misc<<<1, 256, 0, stream>>>(alpha1, alphaO, zerosO);
}

// Round 2
// 413.890 us; speedup vs baseline: 4.8199x; 4.8199x over previous
//
#include <hip/hip_runtime.h>
#include <hip/hip_bf16.h>

#define B_ 4
#define N_ 16384
#define HID_ 512
#define H_ 8
#define M_ 32
#define D_ 64
#define HM_ 256

typedef __hip_bfloat16 bf16;
typedef __bf16 bf16x8 __attribute__((ext_vector_type(8)));
typedef float f32x4 __attribute__((ext_vector_type(4)));

__device__ __forceinline__ void gl_lds16(const bf16* g, bf16* l) {
    __builtin_amdgcn_global_load_lds(
        (const __attribute__((address_space(1))) void*)g,
        (__attribute__((address_space(3))) void*)l, 16, 0, 0);
}

// ---------------- MFMA GEMM core: C[128x128] tile, A[row][lda] bf16, B^T[col][ldb] bf16.
// 256 threads = 4 waves (2x2), each wave a 64x64 sub-tile (4x4 16x16 frags), BK=64.
__device__ __forceinline__ void mfma_core(
        const bf16* __restrict__ Ag, const bf16* __restrict__ Bg,
        long long arow0, int bcol0, int lda, int ldb, int kiters,
        bf16* As, bf16* Bs, f32x4 acc[4][4]) {
    const int t = threadIdx.x;
    const int l = t & 63, w = t >> 6;
    const int wm = w >> 1, wn = w & 1;
    const int srow = l >> 3;          // 0..7
    const int skel = (l & 7) * 8;     // k elem offset
    for (int kt = 0; kt < kiters; ++kt) {
        const int kk = kt * 64;
#pragma unroll
        for (int j = 0; j < 4; ++j) {
            int q = j * 4 + w;        // wave-uniform
            gl_lds16(Ag + (arow0 + q * 8 + srow) * (long long)lda + kk + skel, As + q * 512);
        }
#pragma unroll
        for (int j = 0; j < 4; ++j) {
            int q = j * 4 + w;
            gl_lds16(Bg + (long long)(bcol0 + q * 8 + srow) * ldb + kk + skel, Bs + q * 512);
        }
        __syncthreads();
#pragma unroll
        for (int ks = 0; ks < 64; ks += 32) {
            bf16x8 af[4], bfr[4];
#pragma unroll
            for (int mf = 0; mf < 4; ++mf)
                af[mf] = *(const bf16x8*)(As + (wm * 64 + mf * 16 + (l & 15)) * 64 + ks + (l >> 4) * 8);
#pragma unroll
            for (int nf = 0; nf < 4; ++nf)
                bfr[nf] = *(const bf16x8*)(Bs + (wn * 64 + nf * 16 + (l & 15)) * 64 + ks + (l >> 4) * 8);
#pragma unroll
            for (int mf = 0; mf < 4; ++mf)
#pragma unroll
                for (int nf = 0; nf < 4; ++nf)
                    acc[mf][nf] = __builtin_amdgcn_mfma_f32_16x16x32_bf16(af[mf], bfr[nf], acc[mf][nf], 0, 0, 0);
        }
        __syncthreads();
    }
}

// ---------------- cast f32 -> bf16, 4 elems/thread
__global__ __launch_bounds__(256) void k_cast4(const float* __restrict__ s,
        ushort* __restrict__ d) {
    long long i = (long long)blockIdx.x * 256 + threadIdx.x;
    float4 v = reinterpret_cast<const float4*>(s)[i];
    ushort4 o;
    bf16 a0 = __float2bfloat16(v.x), a1 = __float2bfloat16(v.y);
    bf16 a2 = __float2bfloat16(v.z), a3 = __float2bfloat16(v.w);
    o.x = *(ushort*)&a0; o.y = *(ushort*)&a1; o.z = *(ushort*)&a2; o.w = *(ushort*)&a3;
    reinterpret_cast<ushort4*>(d)[i] = o;
}

// ---------------- wf_bt[o][k] = sum_m mix1_w[o, h*32+m] * wtq[h,m,d], k=h*64+d  (bf16, B^T form)
__global__ __launch_bounds__(256) void k_wfused(const float* __restrict__ mix1,
        const float* __restrict__ wtq, bf16* __restrict__ wf_bt) {
    const int idx = blockIdx.x * 256 + threadIdx.x;   // < 131072
    const int o = idx >> 9, k = idx & 511;
    const int h = k >> 6, dd = k & 63;
    float s = 0.f;
#pragma unroll
    for (int m = 0; m < 32; ++m)
        s += mix1[(long long)o * 256 + h * 32 + m] * wtq[((long long)h * 32 + m) * 64 + dd];
    wf_bt[(long long)o * 512 + k] = __float2bfloat16(s);
}

// ---------------- K1: kv = xb @ wkvb^T + bkv -> xk,xv bf16
__global__ __launch_bounds__(256) void k1_mfma(const bf16* __restrict__ xb,
        const bf16* __restrict__ wkvb, const float* __restrict__ bkv,
        bf16* __restrict__ xk, bf16* __restrict__ xv) {
    __shared__ bf16 As[128 * 64], Bs[128 * 64];
    f32x4 acc[4][4];
#pragma unroll
    for (int i = 0; i < 4; ++i)
#pragma unroll
        for (int j = 0; j < 4; ++j) acc[i][j] = (f32x4)(0.0f);
    const long long arow0 = (long long)blockIdx.y * 128;
    const int bcol0 = blockIdx.x * 128;
    mfma_core(xb, wkvb, arow0, bcol0, 512, 512, 8, As, Bs, acc);
    const int l = threadIdx.x & 63, w = threadIdx.x >> 6;
    const int wm = w >> 1, wn = w & 1;
#pragma unroll
    for (int mf = 0; mf < 4; ++mf) {
#pragma unroll
        for (int nf = 0; nf < 4; ++nf) {
            int col = bcol0 + wn * 64 + nf * 16 + (l & 15);
            float bv = bkv[col];
#pragma unroll
            for (int r = 0; r < 4; ++r) {
                long long row = arow0 + wm * 64 + mf * 16 + (l >> 4) * 4 + r;
                bf16 hv = __float2bfloat16(acc[mf][nf][r] + bv);
                if (col < 512) xk[row * 512 + col] = hv;
                else           xv[row * 512 + (col - 512)] = hv;
            }
        }
    }
}

// ---------------- K2: scores = (xk @ wf_bt^T) * alpha[h] -> bf16 [row][256]
__global__ __launch_bounds__(256) void k2_mfma(const bf16* __restrict__ xk,
        const bf16* __restrict__ wf_bt, const float* __restrict__ alpha1,
        bf16* __restrict__ sc) {
    __shared__ bf16 As[128 * 64], Bs[128 * 64];
    f32x4 acc[4][4];
#pragma unroll
    for (int i = 0; i < 4; ++i)
#pragma unroll
        for (int j = 0; j < 4; ++j) acc[i][j] = (f32x4)(0.0f);
    const long long arow0 = (long long)blockIdx.y * 128;
    const int bcol0 = blockIdx.x * 128;
    mfma_core(xk, wf_bt, arow0, bcol0, 512, 512, 8, As, Bs, acc);
    const int l = threadIdx.x & 63, w = threadIdx.x >> 6;
    const int wm = w >> 1, wn = w & 1;
#pragma unroll
    for (int mf = 0; mf < 4; ++mf) {
#pragma unroll
        for (int nf = 0; nf < 4; ++nf) {
            int col = bcol0 + wn * 64 + nf * 16 + (l & 15);
            float al = alpha1[col >> 5];
#pragma unroll
            for (int r = 0; r < 4; ++r) {
                long long row = arow0 + wm * 64 + mf * 16 + (l >> 4) * 4 + r;
                sc[row * 256 + col] = __float2bfloat16(acc[mf][nf][r] * al);
            }
        }
    }
}

// ---------------- softmax over m-groups (32) per (b,h,n); writes sw f32 [b][c][N] and sw_bt bf16 [row][256]
__global__ __launch_bounds__(256) void k_softmax(const bf16* __restrict__ sc,
        float* __restrict__ swout, bf16* __restrict__ sw_bt) {
    __shared__ float T[32][257];
    const int t = threadIdx.x;
    const int b = blockIdx.y;
    const int n0 = blockIdx.x * 32;
    const long long rb = (long long)b * N_ + n0;
    for (int i = 0; i < 32; ++i)
        T[i][t] = __bfloat162float(sc[(rb + i) * 256 + t]);
    __syncthreads();
    const int nl = t & 31, h = t >> 5;
    float v[32];
    float mx = -1e30f;
#pragma unroll
    for (int i = 0; i < 32; ++i) { v[i] = T[nl][h * 32 + i]; mx = fmaxf(mx, v[i]); }
    float sum = 0.f;
#pragma unroll
    for (int i = 0; i < 32; ++i) { v[i] = __expf(v[i] - mx); sum += v[i]; }
    float rinv = 1.f / sum;
#pragma unroll
    for (int i = 0; i < 32; ++i) T[nl][h * 32 + i] = v[i] * rinv;
    __syncthreads();
#pragma unroll
    for (int jo = 0; jo < 32; ++jo) {
        int o = h * 32 + jo;
        swout[((long long)b * HM_ + o) * N_ + n0 + nl] = T[nl][o];
    }
    for (int i = 0; i < 32; ++i)
        sw_bt[(rb + i) * 256 + t] = __float2bfloat16(T[i][t]);
}

// ---------------- swsum[b*256+c] = sum_n sw
__global__ __launch_bounds__(256) void k_swsum(const float* __restrict__ sw,
        float* __restrict__ swsum) {
    __shared__ float red[256];
    const int t = threadIdx.x;
    const long long base = (long long)blockIdx.x * N_;
    float s = 0.f;
    for (int i = 0; i < N_ / 256; ++i) s += sw[base + i * 256 + t];
    red[t] = s; __syncthreads();
    for (int w = 128; w >= 1; w >>= 1) {
        if (t < w) red[t] += red[t + w];
        __syncthreads();
    }
    if (t == 0) swsum[blockIdx.x] = red[0];
}

// ---------------- K3: tok partials over n-chunks: tok_part[bh][chunk][m][d]
__global__ __launch_bounds__(256) void k3_tok(const float* __restrict__ sw,
        const bf16* __restrict__ xv, float* __restrict__ tok_part) {
    __shared__ __align__(16) float swsT[256][36];
    const int t = threadIdx.x;
    const int d = t & 63, g = t >> 6;
    const int chunk = blockIdx.x;
    const int bh = blockIdx.y;
    const int n0 = chunk * 256;
    const int b = bh >> 3, h = bh & 7;
#pragma unroll
    for (int i = 0; i < 32; ++i)
        swsT[t][i] = sw[((long long)bh * 32 + i) * N_ + n0 + t];
    __syncthreads();
    float acc[32] = {};
    const long long xvbase = ((long long)b * N_ + n0 + g * 64) * 512 + h * 64 + d;
    for (int ni = 0; ni < 64; ++ni) {
        int nl = g * 64 + ni;
        float xvv = __bfloat162float(xv[xvbase + (long long)ni * 512]);
#pragma unroll
        for (int m4 = 0; m4 < 8; ++m4) {
            float4 s4 = *reinterpret_cast<const float4*>(&swsT[nl][m4 * 4]);
            acc[m4 * 4 + 0] += s4.x * xvv;
            acc[m4 * 4 + 1] += s4.y * xvv;
            acc[m4 * 4 + 2] += s4.z * xvv;
            acc[m4 * 4 + 3] += s4.w * xvv;
        }
    }
    __syncthreads();
    float* red = &swsT[0][0];
#pragma unroll
    for (int m = 0; m < 32; ++m) red[(g * 32 + m) * 64 + d] = acc[m];
    __syncthreads();
#pragma unroll
    for (int i = 0; i < 8; ++i) {
        int idx = i * 256 + t;
        int m = idx >> 6, dd = idx & 63;
        float s = red[m * 64 + dd] + red[(32 + m) * 64 + dd]
                + red[(64 + m) * 64 + dd] + red[(96 + m) * 64 + dd];
        tok_part[(((long long)bh * 64 + chunk) * 32 + m) * 64 + dd] = s;
    }
}

// ---------------- K4a: sum chunks, normalize, LayerNorm -> tok_ln (B,M,HID)
__global__ __launch_bounds__(64) void k4a_ln(const float* __restrict__ tok_part,
        const float* __restrict__ swsum, const float* __restrict__ ln_w,
        const float* __restrict__ ln_b, float* __restrict__ tok_ln) {
    const int bid = blockIdx.x;
    const int bh = bid >> 5, m = bid & 31;
    const int d = threadIdx.x;
    float s = 0.f;
    for (int ch = 0; ch < 64; ++ch)
        s += tok_part[(((long long)bh * 64 + ch) * 32 + m) * 64 + d];
    float tokv = s / (swsum[bid] + 1e-5f);
    float mu = tokv;
#pragma unroll
    for (int mk = 32; mk >= 1; mk >>= 1) mu += __shfl_xor(mu, mk, 64);
    mu *= (1.f / 64.f);
    float df = tokv - mu;
    float var = df * df;
#pragma unroll
    for (int mk = 32; mk >= 1; mk >>= 1) var += __shfl_xor(var, mk, 64);
    var *= (1.f / 64.f);
    float y = df * rsqrtf(var + 1e-5f) * ln_w[d] + ln_b[d];
    const int b = bh >> 3, h = bh & 7;
    tok_ln[((long long)b * 32 + m) * 512 + h * 64 + d] = y;
}

// ---------------- K4b: qkv = tok_ln @ wqkv^T
__global__ __launch_bounds__(256) void k4b_qkv(const float* __restrict__ tok_ln,
        const float* __restrict__ wqkv, float* __restrict__ qkv) {
    const int idx = blockIdx.x * 256 + threadIdx.x;
    const int row = idx / 1536, j = idx % 1536;
    float s = 0.f;
    for (int k = 0; k < 512; ++k)
        s += tok_ln[(long long)row * 512 + k] * wqkv[(long long)j * 512 + k];
    qkv[idx] = s;
}

// ---------------- K4c: inner MHA (M=32) per (b,h)
__global__ __launch_bounds__(256) void k4c_attn(const float* __restrict__ qkv,
        float* __restrict__ out_tok, float* __restrict__ attn_out) {
    __shared__ float qsT[64][33], ksT[64][33], vsT[64][33];
    __shared__ float att[32][33];
    __shared__ float rinv[32];
    const int t = threadIdx.x;
    const int bid = blockIdx.x;
    const int b = bid >> 3, h = bid & 7;
#pragma unroll
    for (int i = 0; i < 8; ++i) {
        int idx = i * 256 + t;
        int mi = idx >> 6, dd = idx & 63;
        long long base = ((long long)b * 32 + mi) * 1536 + h * 64 + dd;
        qsT[dd][mi] = qkv[base];
        ksT[dd][mi] = qkv[base + 512];
        vsT[dd][mi] = qkv[base + 1024];
    }
    __syncthreads();
#pragma unroll
    for (int i = 0; i < 4; ++i) {
        int idx = i * 256 + t;
        int qi = idx >> 5, ki = idx & 31;
        float s = 0.f;
#pragma unroll
        for (int dd = 0; dd < 64; ++dd) s += qsT[dd][qi] * ksT[dd][ki];
        att[qi][ki] = s * 0.125f;
    }
    __syncthreads();
    if (t < 32) {
        float mx = -1e30f;
        for (int k = 0; k < 32; ++k) mx = fmaxf(mx, att[t][k]);
        float sum = 0.f;
        for (int k = 0; k < 32; ++k) { float e = __expf(att[t][k] - mx); att[t][k] = e; sum += e; }
        rinv[t] = 1.f / sum;
    }
    __syncthreads();
#pragma unroll
    for (int i = 0; i < 4; ++i) {
        int idx = i * 256 + t;
        int qi = idx >> 5, ki = idx & 31;
        float a = att[qi][ki] * rinv[qi];
        att[qi][ki] = a;
        attn_out[(long long)bid * 1024 + qi * 32 + ki] = a;
    }
    __syncthreads();
#pragma unroll
    for (int i = 0; i < 8; ++i) {
        int idx = i * 256 + t;
        int qi = idx >> 6, dd = idx & 63;
        float s = 0.f;
#pragma unroll
        for (int ki = 0; ki < 32; ++ki) s += att[qi][ki] * vsT[dd][ki];
        out_tok[((long long)bid * 32 + qi) * 64 + dd] = s;
    }
}

// ---------------- K5: W2b[b][o][c] bf16 = sum_d wout[o, h*64+d] * out_tok[b,h,m,d]
__global__ __launch_bounds__(256) void k5_w2(const float* __restrict__ wout,
        const float* __restrict__ out_tok, bf16* __restrict__ W2) {
    const int bid = blockIdx.x;
    const int b = bid >> 9, o = bid & 511;
    const int t = threadIdx.x;
    const int h = t >> 5, m = t & 31;
    float s = 0.f;
#pragma unroll
    for (int dd = 0; dd < 64; ++dd)
        s += wout[(long long)o * 512 + h * 64 + dd]
           * out_tok[(((long long)b * 8 + h) * 32 + m) * 64 + dd];
    W2[(long long)bid * 256 + t] = __float2bfloat16(s);
}

// ---------------- K6: out[b][n][o] = sw_bt[b*N+n][c] @ W2b[b][o][c]^T + bout
__global__ __launch_bounds__(256) void k6_mfma(const bf16* __restrict__ sw_bt,
        const bf16* __restrict__ W2, const float* __restrict__ bout,
        float* __restrict__ out) {
    __shared__ bf16 As[128 * 64], Bs[128 * 64];
    f32x4 acc[4][4];
#pragma unroll
    for (int i = 0; i < 4; ++i)
#pragma unroll
        for (int j = 0; j < 4; ++j) acc[i][j] = (f32x4)(0.0f);
    const int b = blockIdx.z;
    const long long arow0 = (long long)blockIdx.y * 128;
    const int bcol0 = blockIdx.x * 128;
    mfma_core(sw_bt + (long long)b * N_ * 256, W2 + (long long)b * 512 * 256,
              arow0, bcol0, 256, 256, 4, As, Bs, acc);
    const int l = threadIdx.x & 63, w = threadIdx.x >> 6;
    const int wm = w >> 1, wn = w & 1;
#pragma unroll
    for (int mf = 0; mf < 4; ++mf) {
#pragma unroll
        for (int nf = 0; nf < 4; ++nf) {
            int col = bcol0 + wn * 64 + nf * 16 + (l & 15);
            float bv = bout[col];
#pragma unroll
            for (int r = 0; r < 4; ++r) {
                long long row = arow0 + wm * 64 + mf * 16 + (l >> 4) * 4 + r;
                out[((long long)b * N_ + row) * 512 + col] = acc[mf][nf][r] + bv;
            }
        }
    }
}

// ---------------- misc outputs
__global__ void k_misc(const float* __restrict__ alpha1,
        float* __restrict__ outA, float* __restrict__ outZ) {
    int t = threadIdx.x;
    if (t < 8) outA[t] = alpha1[t];
    outZ[t] = 0.f;
}

extern "C" void kernel_launch(void* const* d_in, const int* in_sizes, int n_in,
                              void* d_out, int out_size, void* d_ws, size_t ws_size,
                              hipStream_t stream) {
    const float* x      = (const float*)d_in[0];
    const float* wkv    = (const float*)d_in[1];
    const float* bkv    = (const float*)d_in[2];
    const float* wtq    = (const float*)d_in[3];
    const float* alpha1 = (const float*)d_in[4];
    const float* mix1_w = (const float*)d_in[5];
    const float* ln1_w  = (const float*)d_in[6];
    const float* ln1_b  = (const float*)d_in[7];
    const float* wqkv   = (const float*)d_in[8];
    const float* wout   = (const float*)d_in[9];
    const float* bout   = (const float*)d_in[10];

    float* out    = (float*)d_out;
    float* swout  = out + 33554432LL;
    float* alphaO = out + 50331648LL;
    float* zerosO = out + 50331656LL;
    float* attnO  = out + 50331912LL;

    char* ws = (char*)d_ws;
    bf16*  xb       = (bf16*)(ws);                        // 64 MiB (x cast); dead after k1
    bf16*  sc       = (bf16*)(ws);                        // 32 MiB scores (reuse xb)
    bf16*  sw_bt    = (bf16*)(ws + 33554432LL);           // 32 MiB (reuse xb)
    bf16*  xk       = (bf16*)(ws + 67108864LL);           // 64 MiB
    bf16*  xv       = (bf16*)(ws + 134217728LL);          // 64 MiB
    float* tok_part = (float*)(ws + 201326592LL);         // 16 MiB
    float* swsum    = (float*)(ws + 218103808LL);         // 4 KiB
    float* tok_ln   = (float*)(ws + 218107904LL);         // 256 KiB
    float* qkv      = (float*)(ws + 218370048LL);         // 768 KiB
    float* out_tok  = (float*)(ws + 219156480LL);         // 256 KiB
    bf16*  W2b      = (bf16*)(ws + 219418624LL);          // 1 MiB
    bf16*  wkvb     = (bf16*)(ws + 220467200LL);          // 1 MiB
    bf16*  wf_bt    = (bf16*)(ws + 221515776LL);          // 256 KiB

    k_cast4<<<32768, 256, 0, stream>>>(x, (ushort*)xb);
    k_cast4<<<512, 256, 0, stream>>>(wkv, (ushort*)wkvb);
    k_wfused<<<512, 256, 0, stream>>>(mix1_w, wtq, wf_bt);
    k1_mfma<<<dim3(8, 512), 256, 0, stream>>>(xb, wkvb, bkv, xk, xv);
    k2_mfma<<<dim3(2, 512), 256, 0, stream>>>(xk, wf_bt, alpha1, sc);
    k_softmax<<<dim3(512, 4), 256, 0, stream>>>(sc, swout, sw_bt);
    k_swsum<<<1024, 256, 0, stream>>>(swout, swsum);
    k3_tok<<<dim3(64, 32), 256, 0, stream>>>(swout, xv, tok_part);
    k4a_ln<<<1024, 64, 0, stream>>>(tok_part, swsum, ln1_w, ln1_b, tok_ln);
    k4b_qkv<<<768, 256, 0, stream>>>(tok_ln, wqkv, qkv);
    k4c_attn<<<32, 256, 0, stream>>>(qkv, out_tok, attnO);
    k5_w2<<<2048, 256, 0, stream>>>(wout, out_tok, W2b);
    k6_mfma<<<dim3(4, 128, 4), 256, 0, stream>>>(sw_bt, W2b, bout, out);
    k_misc<<<1, 256, 0, stream>>>(alpha1, alphaO, zerosO);
}

// Round 3
// 375.258 us; speedup vs baseline: 5.3161x; 1.1029x over previous
//
#include <hip/hip_runtime.h>
#include <hip/hip_bf16.h>

#define B_ 4
#define N_ 16384
#define HID_ 512
#define H_ 8
#define M_ 32
#define D_ 64
#define HM_ 256

typedef __hip_bfloat16 bf16;
typedef __bf16 bf16x8 __attribute__((ext_vector_type(8)));
typedef float f32x4 __attribute__((ext_vector_type(4)));

__device__ __forceinline__ void gl_lds16(const bf16* g, bf16* l) {
    __builtin_amdgcn_global_load_lds(
        (const __attribute__((address_space(1))) void*)g,
        (__attribute__((address_space(3))) void*)l, 16, 0, 0);
}

// XCD-aware bijective block remap (requires nwg % 8 == 0)
__device__ __forceinline__ int xcd_swz(int lin, int nwg) {
    return (lin & 7) * (nwg >> 3) + (lin >> 3);
}

// ---------------- MFMA GEMM core: C[128x128] tile, A[row][lda] bf16, B^T[col][ldb] bf16.
__device__ __forceinline__ void mfma_core(
        const bf16* __restrict__ Ag, const bf16* __restrict__ Bg,
        long long arow0, int bcol0, int lda, int ldb, int kiters,
        bf16* As, bf16* Bs, f32x4 acc[4][4]) {
    const int t = threadIdx.x;
    const int l = t & 63, w = t >> 6;
    const int wm = w >> 1, wn = w & 1;
    const int srow = l >> 3;
    const int skel = (l & 7) * 8;
    for (int kt = 0; kt < kiters; ++kt) {
        const int kk = kt * 64;
#pragma unroll
        for (int j = 0; j < 4; ++j) {
            int q = j * 4 + w;
            gl_lds16(Ag + (arow0 + q * 8 + srow) * (long long)lda + kk + skel, As + q * 512);
        }
#pragma unroll
        for (int j = 0; j < 4; ++j) {
            int q = j * 4 + w;
            gl_lds16(Bg + (long long)(bcol0 + q * 8 + srow) * ldb + kk + skel, Bs + q * 512);
        }
        __syncthreads();
#pragma unroll
        for (int ks = 0; ks < 64; ks += 32) {
            bf16x8 af[4], bfr[4];
#pragma unroll
            for (int mf = 0; mf < 4; ++mf)
                af[mf] = *(const bf16x8*)(As + (wm * 64 + mf * 16 + (l & 15)) * 64 + ks + (l >> 4) * 8);
#pragma unroll
            for (int nf = 0; nf < 4; ++nf)
                bfr[nf] = *(const bf16x8*)(Bs + (wn * 64 + nf * 16 + (l & 15)) * 64 + ks + (l >> 4) * 8);
#pragma unroll
            for (int mf = 0; mf < 4; ++mf)
#pragma unroll
                for (int nf = 0; nf < 4; ++nf)
                    acc[mf][nf] = __builtin_amdgcn_mfma_f32_16x16x32_bf16(af[mf], bfr[nf], acc[mf][nf], 0, 0, 0);
        }
        __syncthreads();
    }
}

// ---------------- cast f32 -> bf16, 4 elems/thread
__global__ __launch_bounds__(256) void k_cast4(const float* __restrict__ s,
        ushort* __restrict__ d) {
    long long i = (long long)blockIdx.x * 256 + threadIdx.x;
    float4 v = reinterpret_cast<const float4*>(s)[i];
    ushort4 o;
    bf16 a0 = __float2bfloat16(v.x), a1 = __float2bfloat16(v.y);
    bf16 a2 = __float2bfloat16(v.z), a3 = __float2bfloat16(v.w);
    o.x = *(ushort*)&a0; o.y = *(ushort*)&a1; o.z = *(ushort*)&a2; o.w = *(ushort*)&a3;
    reinterpret_cast<ushort4*>(d)[i] = o;
}

// ---------------- wf_bt[o][k] = sum_m mix1_w[o, h*32+m] * wtq[h,m,d], k=h*64+d
__global__ __launch_bounds__(256) void k_wfused(const float* __restrict__ mix1,
        const float* __restrict__ wtq, bf16* __restrict__ wf_bt) {
    const int idx = blockIdx.x * 256 + threadIdx.x;
    const int o = idx >> 9, k = idx & 511;
    const int h = k >> 6, dd = k & 63;
    float s = 0.f;
#pragma unroll
    for (int m = 0; m < 32; ++m)
        s += mix1[(long long)o * 256 + h * 32 + m] * wtq[((long long)h * 32 + m) * 64 + dd];
    wf_bt[(long long)o * 512 + k] = __float2bfloat16(s);
}

// ---------------- K1: kv = xb @ wkvb^T + bkv -> xk,xv bf16
__global__ __launch_bounds__(256) void k1_mfma(const bf16* __restrict__ xb,
        const bf16* __restrict__ wkvb, const float* __restrict__ bkv,
        bf16* __restrict__ xk, bf16* __restrict__ xv) {
    __shared__ bf16 As[128 * 64], Bs[128 * 64];
    f32x4 acc[4][4];
#pragma unroll
    for (int i = 0; i < 4; ++i)
#pragma unroll
        for (int j = 0; j < 4; ++j) acc[i][j] = (f32x4)(0.0f);
    const int wg = xcd_swz(blockIdx.y * 8 + blockIdx.x, 4096);
    const int bx = wg & 7, by = wg >> 3;
    const long long arow0 = (long long)by * 128;
    const int bcol0 = bx * 128;
    mfma_core(xb, wkvb, arow0, bcol0, 512, 512, 8, As, Bs, acc);
    const int l = threadIdx.x & 63, w = threadIdx.x >> 6;
    const int wm = w >> 1, wn = w & 1;
#pragma unroll
    for (int mf = 0; mf < 4; ++mf) {
#pragma unroll
        for (int nf = 0; nf < 4; ++nf) {
            int col = bcol0 + wn * 64 + nf * 16 + (l & 15);
            float bv = bkv[col];
#pragma unroll
            for (int r = 0; r < 4; ++r) {
                long long row = arow0 + wm * 64 + mf * 16 + (l >> 4) * 4 + r;
                bf16 hv = __float2bfloat16(acc[mf][nf][r] + bv);
                if (col < 512) xk[row * 512 + col] = hv;
                else           xv[row * 512 + (col - 512)] = hv;
            }
        }
    }
}

// ---------------- K2: scores = (xk @ wf_bt^T) * alpha[h] -> bf16 [row][256]
__global__ __launch_bounds__(256) void k2_mfma(const bf16* __restrict__ xk,
        const bf16* __restrict__ wf_bt, const float* __restrict__ alpha1,
        bf16* __restrict__ sc) {
    __shared__ bf16 As[128 * 64], Bs[128 * 64];
    f32x4 acc[4][4];
#pragma unroll
    for (int i = 0; i < 4; ++i)
#pragma unroll
        for (int j = 0; j < 4; ++j) acc[i][j] = (f32x4)(0.0f);
    const int wg = xcd_swz(blockIdx.y * 2 + blockIdx.x, 1024);
    const int bx = wg & 1, by = wg >> 1;
    const long long arow0 = (long long)by * 128;
    const int bcol0 = bx * 128;
    mfma_core(xk, wf_bt, arow0, bcol0, 512, 512, 8, As, Bs, acc);
    const int l = threadIdx.x & 63, w = threadIdx.x >> 6;
    const int wm = w >> 1, wn = w & 1;
#pragma unroll
    for (int mf = 0; mf < 4; ++mf) {
#pragma unroll
        for (int nf = 0; nf < 4; ++nf) {
            int col = bcol0 + wn * 64 + nf * 16 + (l & 15);
            float al = alpha1[col >> 5];
#pragma unroll
            for (int r = 0; r < 4; ++r) {
                long long row = arow0 + wm * 64 + mf * 16 + (l >> 4) * 4 + r;
                sc[row * 256 + col] = __float2bfloat16(acc[mf][nf][r] * al);
            }
        }
    }
}

// ---------------- softmax over m per (b,h,n); writes sw f32 [b][c][N], sw_bt bf16 [row][256],
// and per-block swsum partials part[b][nblk][256]
__global__ __launch_bounds__(256) void k_softmax(const bf16* __restrict__ sc,
        float* __restrict__ swout, bf16* __restrict__ sw_bt,
        float* __restrict__ part) {
    __shared__ float T[32][257];
    const int t = threadIdx.x;
    const int b = blockIdx.y;
    const int n0 = blockIdx.x * 32;
    const long long rb = (long long)b * N_ + n0;
    for (int i = 0; i < 32; ++i)
        T[i][t] = __bfloat162float(sc[(rb + i) * 256 + t]);
    __syncthreads();
    const int nl = t & 31, h = t >> 5;
    float v[32];
    float mx = -1e30f;
#pragma unroll
    for (int i = 0; i < 32; ++i) { v[i] = T[nl][h * 32 + i]; mx = fmaxf(mx, v[i]); }
    float sum = 0.f;
#pragma unroll
    for (int i = 0; i < 32; ++i) { v[i] = __expf(v[i] - mx); sum += v[i]; }
    float rinv = 1.f / sum;
#pragma unroll
    for (int i = 0; i < 32; ++i) T[nl][h * 32 + i] = v[i] * rinv;
    __syncthreads();
#pragma unroll
    for (int jo = 0; jo < 32; ++jo) {
        int o = h * 32 + jo;
        swout[((long long)b * HM_ + o) * N_ + n0 + nl] = T[nl][o];
    }
    for (int i = 0; i < 32; ++i)
        sw_bt[(rb + i) * 256 + t] = __float2bfloat16(T[i][t]);
    float s = 0.f;
#pragma unroll
    for (int i = 0; i < 32; ++i) s += T[i][t];
    part[((long long)b * 512 + blockIdx.x) * 256 + t] = s;
}

// ---------------- swsum reduce: swsum[b*256+c] = sum_nblk part
__global__ __launch_bounds__(256) void k_swsum2(const float* __restrict__ part,
        float* __restrict__ swsum) {
    const int b = blockIdx.x, c = threadIdx.x;
    float s = 0.f;
    for (int nb = 0; nb < 512; ++nb)
        s += part[((long long)b * 512 + nb) * 256 + c];
    swsum[b * 256 + c] = s;
}

// ---------------- K3: register-tiled outer-product: tok_part[bh][chunk][m][d]
__global__ __launch_bounds__(256) void k3_tok(const float* __restrict__ sw,
        const bf16* __restrict__ xv, float* __restrict__ tok_part) {
    __shared__ __align__(16) float smem[17408];          // 68 KiB
    float (*swsT)[36] = reinterpret_cast<float(*)[36]>(smem);   // [256 nl][36] (32 m used)
    bf16* xvs = reinterpret_cast<bf16*>(smem + 9216);           // [256 nl][64 d]
    const int t = threadIdx.x;
    const int chunk = blockIdx.x;   // 64
    const int bh = blockIdx.y;      // 32
    const int n0 = chunk * 256;
    const int b = bh >> 3, h = bh & 7;
    // stage sw transposed: [nl][m], b128 writes (2-way, free)
    const long long swbase = ((long long)bh * 32) * N_ + n0;
#pragma unroll
    for (int p = 0; p < 8; ++p) {
        float4 v;
        v.x = sw[swbase + (long long)(p * 4 + 0) * N_ + t];
        v.y = sw[swbase + (long long)(p * 4 + 1) * N_ + t];
        v.z = sw[swbase + (long long)(p * 4 + 2) * N_ + t];
        v.w = sw[swbase + (long long)(p * 4 + 3) * N_ + t];
        *reinterpret_cast<float4*>(&swsT[t][p * 4]) = v;
    }
    // stage xv: b32 chunks (2 bf16 each), conflict-free
    {
        const uint* xg = reinterpret_cast<const uint*>(xv + ((long long)b * N_ + n0) * 512 + h * 64);
        uint* xls = reinterpret_cast<uint*>(xvs);
#pragma unroll
        for (int p = 0; p < 32; ++p) {
            int idx = p * 256 + t;
            int nl = idx >> 5, prt = idx & 31;
            xls[nl * 32 + prt] = xg[(long long)nl * 256 + prt];
        }
    }
    __syncthreads();
    const int l = t & 63, w = t >> 6;
    const int nlh = l >> 5, mtile = (l >> 3) & 3, dtile = l & 7;
    const int m0 = mtile * 8, d0 = dtile * 8;
    float acc[8][8] = {};
    const int wbase = w * 64;
    for (int i = 0; i < 32; ++i) {
        int nl = wbase + i * 2 + nlh;
        float4 s0 = *reinterpret_cast<const float4*>(&swsT[nl][m0]);
        float4 s1 = *reinterpret_cast<const float4*>(&swsT[nl][m0 + 4]);
        uint4 xi = *reinterpret_cast<const uint4*>(&xvs[nl * 64 + d0]);
        float xvf[8];
        xvf[0] = __uint_as_float(xi.x << 16); xvf[1] = __uint_as_float(xi.x & 0xffff0000u);
        xvf[2] = __uint_as_float(xi.y << 16); xvf[3] = __uint_as_float(xi.y & 0xffff0000u);
        xvf[4] = __uint_as_float(xi.z << 16); xvf[5] = __uint_as_float(xi.z & 0xffff0000u);
        xvf[6] = __uint_as_float(xi.w << 16); xvf[7] = __uint_as_float(xi.w & 0xffff0000u);
        float sm[8] = {s0.x, s0.y, s0.z, s0.w, s1.x, s1.y, s1.z, s1.w};
#pragma unroll
        for (int mi = 0; mi < 8; ++mi)
#pragma unroll
            for (int di = 0; di < 8; ++di)
                acc[mi][di] += sm[mi] * xvf[di];
    }
    __syncthreads();
    // cross-slice reduce: 8 slices (w*2+nlh) x 2048
    float* red = smem;
    float* rb = red + (w * 2 + nlh) * 2048;
#pragma unroll
    for (int mi = 0; mi < 8; ++mi) {
        float4 lo = {acc[mi][0], acc[mi][1], acc[mi][2], acc[mi][3]};
        float4 hi = {acc[mi][4], acc[mi][5], acc[mi][6], acc[mi][7]};
        *reinterpret_cast<float4*>(&rb[(m0 + mi) * 64 + d0]) = lo;
        *reinterpret_cast<float4*>(&rb[(m0 + mi) * 64 + d0 + 4]) = hi;
    }
    __syncthreads();
#pragma unroll
    for (int pp = 0; pp < 2; ++pp) {
        int idx4 = pp * 1024 + t * 4;
        float4 s = {0.f, 0.f, 0.f, 0.f};
#pragma unroll
        for (int r = 0; r < 8; ++r) {
            float4 v = *reinterpret_cast<const float4*>(&red[r * 2048 + idx4]);
            s.x += v.x; s.y += v.y; s.z += v.z; s.w += v.w;
        }
        *reinterpret_cast<float4*>(&tok_part[((long long)bh * 64 + chunk) * 2048 + idx4]) = s;
    }
}

// ---------------- K4a: sum chunks, normalize, LayerNorm -> tok_ln (B,M,HID)
__global__ __launch_bounds__(64) void k4a_ln(const float* __restrict__ tok_part,
        const float* __restrict__ swsum, const float* __restrict__ ln_w,
        const float* __restrict__ ln_b, float* __restrict__ tok_ln) {
    const int bid = blockIdx.x;
    const int bh = bid >> 5, m = bid & 31;
    const int d = threadIdx.x;
    float s = 0.f;
    for (int ch = 0; ch < 64; ++ch)
        s += tok_part[(((long long)bh * 64 + ch) * 32 + m) * 64 + d];
    float tokv = s / (swsum[bid] + 1e-5f);
    float mu = tokv;
#pragma unroll
    for (int mk = 32; mk >= 1; mk >>= 1) mu += __shfl_xor(mu, mk, 64);
    mu *= (1.f / 64.f);
    float df = tokv - mu;
    float var = df * df;
#pragma unroll
    for (int mk = 32; mk >= 1; mk >>= 1) var += __shfl_xor(var, mk, 64);
    var *= (1.f / 64.f);
    float y = df * rsqrtf(var + 1e-5f) * ln_w[d] + ln_b[d];
    const int b = bh >> 3, h = bh & 7;
    tok_ln[((long long)b * 32 + m) * 512 + h * 64 + d] = y;
}

// ---------------- wqkvT[k][j] = wqkv[j][k]
__global__ __launch_bounds__(256) void k_wqT(const float* __restrict__ wq,
        float* __restrict__ wqT) {
    __shared__ float tile[32][33];
    const int k0 = blockIdx.x * 32;
    const int j0 = blockIdx.y * 32;
    const int tx = threadIdx.x & 31, ty = threadIdx.x >> 5;
#pragma unroll
    for (int r = 0; r < 32; r += 8)
        tile[ty + r][tx] = wq[(long long)(j0 + ty + r) * 512 + k0 + tx];
    __syncthreads();
#pragma unroll
    for (int r = 0; r < 32; r += 8)
        wqT[(long long)(k0 + ty + r) * 1536 + j0 + tx] = tile[tx][ty + r];
}

// ---------------- K4b: qkv = tok_ln @ wqkv^T via transposed weights
__global__ __launch_bounds__(256) void k4b_qkv(const float* __restrict__ tok_ln,
        const float* __restrict__ wqT, float* __restrict__ qkv) {
    const int j = (blockIdx.x % 6) * 256 + threadIdx.x;
    const int r0 = (blockIdx.x / 6) * 4;
    float a0 = 0, a1 = 0, a2 = 0, a3 = 0;
    for (int k = 0; k < 512; ++k) {
        float wv = wqT[(long long)k * 1536 + j];
        a0 += tok_ln[(r0 + 0) * 512 + k] * wv;
        a1 += tok_ln[(r0 + 1) * 512 + k] * wv;
        a2 += tok_ln[(r0 + 2) * 512 + k] * wv;
        a3 += tok_ln[(r0 + 3) * 512 + k] * wv;
    }
    qkv[(long long)(r0 + 0) * 1536 + j] = a0;
    qkv[(long long)(r0 + 1) * 1536 + j] = a1;
    qkv[(long long)(r0 + 2) * 1536 + j] = a2;
    qkv[(long long)(r0 + 3) * 1536 + j] = a3;
}

// ---------------- K4c: inner MHA (M=32) per (b,h)
__global__ __launch_bounds__(256) void k4c_attn(const float* __restrict__ qkv,
        float* __restrict__ out_tok, float* __restrict__ attn_out) {
    __shared__ float qsT[64][33], ksT[64][33], vsT[64][33];
    __shared__ float att[32][33];
    __shared__ float rinv[32];
    const int t = threadIdx.x;
    const int bid = blockIdx.x;
    const int b = bid >> 3, h = bid & 7;
#pragma unroll
    for (int i = 0; i < 8; ++i) {
        int idx = i * 256 + t;
        int mi = idx >> 6, dd = idx & 63;
        long long base = ((long long)b * 32 + mi) * 1536 + h * 64 + dd;
        qsT[dd][mi] = qkv[base];
        ksT[dd][mi] = qkv[base + 512];
        vsT[dd][mi] = qkv[base + 1024];
    }
    __syncthreads();
#pragma unroll
    for (int i = 0; i < 4; ++i) {
        int idx = i * 256 + t;
        int qi = idx >> 5, ki = idx & 31;
        float s = 0.f;
#pragma unroll
        for (int dd = 0; dd < 64; ++dd) s += qsT[dd][qi] * ksT[dd][ki];
        att[qi][ki] = s * 0.125f;
    }
    __syncthreads();
    if (t < 32) {
        float mx = -1e30f;
        for (int k = 0; k < 32; ++k) mx = fmaxf(mx, att[t][k]);
        float sum = 0.f;
        for (int k = 0; k < 32; ++k) { float e = __expf(att[t][k] - mx); att[t][k] = e; sum += e; }
        rinv[t] = 1.f / sum;
    }
    __syncthreads();
#pragma unroll
    for (int i = 0; i < 4; ++i) {
        int idx = i * 256 + t;
        int qi = idx >> 5, ki = idx & 31;
        float a = att[qi][ki] * rinv[qi];
        att[qi][ki] = a;
        attn_out[(long long)bid * 1024 + qi * 32 + ki] = a;
    }
    __syncthreads();
#pragma unroll
    for (int i = 0; i < 8; ++i) {
        int idx = i * 256 + t;
        int qi = idx >> 6, dd = idx & 63;
        float s = 0.f;
#pragma unroll
        for (int ki = 0; ki < 32; ++ki) s += att[qi][ki] * vsT[dd][ki];
        out_tok[((long long)bid * 32 + qi) * 64 + dd] = s;
    }
}

// ---------------- K5: W2b[b][o][c] bf16
__global__ __launch_bounds__(256) void k5_w2(const float* __restrict__ wout,
        const float* __restrict__ out_tok, bf16* __restrict__ W2) {
    const int bid = blockIdx.x;
    const int b = bid >> 9, o = bid & 511;
    const int t = threadIdx.x;
    const int h = t >> 5, m = t & 31;
    float s = 0.f;
#pragma unroll
    for (int dd = 0; dd < 64; ++dd)
        s += wout[(long long)o * 512 + h * 64 + dd]
           * out_tok[(((long long)b * 8 + h) * 32 + m) * 64 + dd];
    W2[(long long)bid * 256 + t] = __float2bfloat16(s);
}

// ---------------- K6: out = sw_bt @ W2b^T + bout
__global__ __launch_bounds__(256) void k6_mfma(const bf16* __restrict__ sw_bt,
        const bf16* __restrict__ W2, const float* __restrict__ bout,
        float* __restrict__ out) {
    __shared__ bf16 As[128 * 64], Bs[128 * 64];
    f32x4 acc[4][4];
#pragma unroll
    for (int i = 0; i < 4; ++i)
#pragma unroll
        for (int j = 0; j < 4; ++j) acc[i][j] = (f32x4)(0.0f);
    const int wg = xcd_swz((blockIdx.z * 128 + blockIdx.y) * 4 + blockIdx.x, 2048);
    const int bx = wg & 3, by = (wg >> 2) & 127, bz = wg >> 9;
    const long long arow0 = (long long)by * 128;
    const int bcol0 = bx * 128;
    mfma_core(sw_bt + (long long)bz * N_ * 256, W2 + (long long)bz * 512 * 256,
              arow0, bcol0, 256, 256, 4, As, Bs, acc);
    const int l = threadIdx.x & 63, w = threadIdx.x >> 6;
    const int wm = w >> 1, wn = w & 1;
#pragma unroll
    for (int mf = 0; mf < 4; ++mf) {
#pragma unroll
        for (int nf = 0; nf < 4; ++nf) {
            int col = bcol0 + wn * 64 + nf * 16 + (l & 15);
            float bv = bout[col];
#pragma unroll
            for (int r = 0; r < 4; ++r) {
                long long row = arow0 + wm * 64 + mf * 16 + (l >> 4) * 4 + r;
                out[((long long)bz * N_ + row) * 512 + col] = acc[mf][nf][r] + bv;
            }
        }
    }
}

// ---------------- misc outputs
__global__ void k_misc(const float* __restrict__ alpha1,
        float* __restrict__ outA, float* __restrict__ outZ) {
    int t = threadIdx.x;
    if (t < 8) outA[t] = alpha1[t];
    outZ[t] = 0.f;
}

extern "C" void kernel_launch(void* const* d_in, const int* in_sizes, int n_in,
                              void* d_out, int out_size, void* d_ws, size_t ws_size,
                              hipStream_t stream) {
    const float* x      = (const float*)d_in[0];
    const float* wkv    = (const float*)d_in[1];
    const float* bkv    = (const float*)d_in[2];
    const float* wtq    = (const float*)d_in[3];
    const float* alpha1 = (const float*)d_in[4];
    const float* mix1_w = (const float*)d_in[5];
    const float* ln1_w  = (const float*)d_in[6];
    const float* ln1_b  = (const float*)d_in[7];
    const float* wqkv   = (const float*)d_in[8];
    const float* wout   = (const float*)d_in[9];
    const float* bout   = (const float*)d_in[10];

    float* out    = (float*)d_out;
    float* swout  = out + 33554432LL;
    float* alphaO = out + 50331648LL;
    float* zerosO = out + 50331656LL;
    float* attnO  = out + 50331912LL;

    char* ws = (char*)d_ws;
    bf16*  xb        = (bf16*)(ws);                      // 64 MiB [cast -> k1]
    bf16*  sc        = (bf16*)(ws);                      // 32 MiB [k2 -> softmax] (over dead xb)
    float* wqkvT     = (float*)(ws);                     // 3 MiB  [wqT -> k4b]    (over dead sc)
    bf16*  sw_bt     = (bf16*)(ws + 33554432LL);         // 32 MiB [softmax -> k6]
    bf16*  xk        = (bf16*)(ws + 67108864LL);         // 64 MiB [k1 -> k2]
    float* swsum_prt = (float*)(ws + 67108864LL);        // 2 MiB  [softmax -> swsum2] (over dead xk)
    bf16*  xv        = (bf16*)(ws + 134217728LL);        // 64 MiB [k1 -> k3]
    float* tok_part  = (float*)(ws + 201326592LL);       // 16 MiB [k3 -> k4a]
    float* swsum     = (float*)(ws + 218103808LL);       // 4 KiB
    float* tok_ln    = (float*)(ws + 218107904LL);       // 256 KiB
    float* qkv       = (float*)(ws + 218370048LL);       // 768 KiB
    float* out_tok   = (float*)(ws + 219156480LL);       // 256 KiB
    bf16*  W2b       = (bf16*)(ws + 219418624LL);        // 1 MiB
    bf16*  wkvb      = (bf16*)(ws + 220467200LL);        // 1 MiB
    bf16*  wf_bt     = (bf16*)(ws + 221515776LL);        // 256 KiB

    k_cast4<<<32768, 256, 0, stream>>>(x, (ushort*)xb);
    k_cast4<<<512, 256, 0, stream>>>(wkv, (ushort*)wkvb);
    k_wfused<<<512, 256, 0, stream>>>(mix1_w, wtq, wf_bt);
    k1_mfma<<<dim3(8, 512), 256, 0, stream>>>(xb, wkvb, bkv, xk, xv);
    k2_mfma<<<dim3(2, 512), 256, 0, stream>>>(xk, wf_bt, alpha1, sc);
    k_softmax<<<dim3(512, 4), 256, 0, stream>>>(sc, swout, sw_bt, swsum_prt);
    k_wqT<<<dim3(16, 48), 256, 0, stream>>>(wqkv, wqkvT);
    k_swsum2<<<4, 256, 0, stream>>>(swsum_prt, swsum);
    k3_tok<<<dim3(64, 32), 256, 0, stream>>>(swout, xv, tok_part);
    k4a_ln<<<1024, 64, 0, stream>>>(tok_part, swsum, ln1_w, ln1_b, tok_ln);
    k4b_qkv<<<192, 256, 0, stream>>>(tok_ln, wqkvT, qkv);
    k4c_attn<<<32, 256, 0, stream>>>(qkv, out_tok, attnO);
    k5_w2<<<2048, 256, 0, stream>>>(wout, out_tok, W2b);
    k6_mfma<<<dim3(4, 128, 4), 256, 0, stream>>>(sw_bt, W2b, bout, out);
    k_misc<<<1, 256, 0, stream>>>(alpha1, alphaO, zerosO);
}